// Round 1
// baseline (259.041 us; speedup 1.0000x reference)
//
#include <hip/hip_runtime.h>

#define NROWS 4096
#define DIM   512
#define MARGIN 0.3f
#define BK  32
#define PAD 68   // 64 + 4 floats; row stride 272 B = 17*16 -> 16B-aligned rows

// ---------------- init: hp=0 bits, hn=+inf bits, hist=0 ----------------
__global__ void init_kernel(unsigned* hp, unsigned* hn, int* hist) {
    int i = blockIdx.x * blockDim.x + threadIdx.x;
    if (i < NROWS) { hp[i] = 0u; hn[i] = 0x7f800000u; }
    if (i < 256) hist[i] = 0;
}

// ---------------- per-row squared norms + label histogram ----------------
__global__ void norms_hist_kernel(const float* __restrict__ X,
                                  const int* __restrict__ labels,
                                  float* __restrict__ norms, int* hist) {
    int wave = threadIdx.x >> 6;
    int lane = threadIdx.x & 63;
    int row  = blockIdx.x * 4 + wave;
    const float4* xr = (const float4*)(X + (size_t)row * DIM);
    float4 a = xr[lane];
    float4 b = xr[lane + 64];
    float s = a.x*a.x + a.y*a.y + a.z*a.z + a.w*a.w
            + b.x*b.x + b.y*b.y + b.z*b.z + b.w*b.w;
    #pragma unroll
    for (int o = 32; o; o >>= 1) s += __shfl_xor(s, o);
    if (lane == 0) {
        norms[row] = s;
        atomicAdd(&hist[labels[row]], 1);
    }
}

// ---------------- fused tile GEMM + masked per-row max/min ----------------
// 64x64 tile per block, 256 threads, 4x4 micro-tile. acc = dot(row_i, row_j).
// sq_dist = n_i + n_j - 2*dot. Reduce per row over the 16 lanes sharing ty,
// then one atomicMax/atomicMin (uint bits, non-negative floats) per row.
__global__ __launch_bounds__(256) void dist_kernel(
        const float* __restrict__ X, const int* __restrict__ labels,
        const float* __restrict__ norms,
        unsigned* __restrict__ hp, unsigned* __restrict__ hn) {
    __shared__ __align__(16) float As[BK][PAD];
    __shared__ __align__(16) float Bs[BK][PAD];
    const int t  = threadIdx.x;
    const int tx = t & 15, ty = t >> 4;
    const int row0 = blockIdx.y * 64, col0 = blockIdx.x * 64;

    float acc[4][4] = {};
    for (int k0 = 0; k0 < DIM; k0 += BK) {
        #pragma unroll
        for (int l = 0; l < 2; ++l) {
            int idx = t + l * 256;
            int r = idx >> 3, fc = idx & 7;   // r: 0..63 row-in-tile, fc: 0..7 float4-in-k
            float4 va = *(const float4*)(X + (size_t)(row0 + r) * DIM + k0 + fc * 4);
            float4 vb = *(const float4*)(X + (size_t)(col0 + r) * DIM + k0 + fc * 4);
            As[fc*4+0][r] = va.x; As[fc*4+1][r] = va.y;
            As[fc*4+2][r] = va.z; As[fc*4+3][r] = va.w;
            Bs[fc*4+0][r] = vb.x; Bs[fc*4+1][r] = vb.y;
            Bs[fc*4+2][r] = vb.z; Bs[fc*4+3][r] = vb.w;
        }
        __syncthreads();
        #pragma unroll
        for (int kk = 0; kk < BK; ++kk) {
            float4 a = *(const float4*)&As[kk][ty * 4];
            float4 b = *(const float4*)&Bs[kk][tx * 4];
            float av[4] = {a.x, a.y, a.z, a.w};
            float bv[4] = {b.x, b.y, b.z, b.w};
            #pragma unroll
            for (int m = 0; m < 4; ++m)
                #pragma unroll
                for (int n = 0; n < 4; ++n)
                    acc[m][n] = fmaf(av[m], bv[n], acc[m][n]);
        }
        __syncthreads();
    }

    // epilogue: mask + per-row reduce on SQUARED distances (sqrt is monotone)
    int li[4], lj[4]; float ni[4], nj[4];
    #pragma unroll
    for (int m = 0; m < 4; ++m) {
        int gi = row0 + ty * 4 + m; li[m] = labels[gi]; ni[m] = norms[gi];
    }
    #pragma unroll
    for (int n = 0; n < 4; ++n) {
        int gj = col0 + tx * 4 + n; lj[n] = labels[gj]; nj[n] = norms[gj];
    }
    #pragma unroll
    for (int m = 0; m < 4; ++m) {
        float pmax = 0.0f;                       // self-dist >= 0, global init 0
        float nmin = __uint_as_float(0x7f800000u);
        #pragma unroll
        for (int n = 0; n < 4; ++n) {
            float sq = fmaxf(ni[m] + nj[n] - 2.0f * acc[m][n], 0.0f);
            if (li[m] == lj[n]) pmax = fmaxf(pmax, sq);
            else                nmin = fminf(nmin, sq);
        }
        // lanes sharing ty are 16 consecutive lanes of the wave
        #pragma unroll
        for (int o = 8; o; o >>= 1) {
            pmax = fmaxf(pmax, __shfl_xor(pmax, o));
            nmin = fminf(nmin, __shfl_xor(nmin, o));
        }
        if (tx == 0) {
            int gi = row0 + ty * 4 + m;
            atomicMax(&hp[gi], __float_as_uint(pmax));
            atomicMin(&hn[gi], __float_as_uint(nmin));
        }
    }
}

// ---------------- finalize: per-row loss, 16 block partials ----------------
__global__ void finalize_kernel(const unsigned* __restrict__ hp,
                                const unsigned* __restrict__ hn,
                                const int* __restrict__ labels,
                                const int* __restrict__ hist,
                                float* __restrict__ part) {
    int i = blockIdx.x * 256 + threadIdx.x;
    float hpd = sqrtf(__uint_as_float(hp[i]));
    float hnd = sqrtf(__uint_as_float(hn[i]));   // may be +inf (no negatives)
    float v = 0.0f;
    if (hist[labels[i]] > 1) v = fmaxf(hpd - hnd + MARGIN, 0.0f);  // relu(-inf)=0
    #pragma unroll
    for (int o = 32; o; o >>= 1) v += __shfl_xor(v, o);
    __shared__ float wsum[4];
    int lane = threadIdx.x & 63, wave = threadIdx.x >> 6;
    if (lane == 0) wsum[wave] = v;
    __syncthreads();
    if (threadIdx.x == 0) part[blockIdx.x] = wsum[0] + wsum[1] + wsum[2] + wsum[3];
}

__global__ void sum_kernel(const float* __restrict__ part, float* __restrict__ out) {
    float v = (threadIdx.x < 16) ? part[threadIdx.x] : 0.0f;
    #pragma unroll
    for (int o = 32; o; o >>= 1) v += __shfl_xor(v, o);
    if (threadIdx.x == 0) out[0] = v / (float)NROWS;
}

extern "C" void kernel_launch(void* const* d_in, const int* in_sizes, int n_in,
                              void* d_out, int out_size, void* d_ws, size_t ws_size,
                              hipStream_t stream) {
    const float* X      = (const float*)d_in[0];
    const int*   labels = (const int*)d_in[1];
    float* ws = (float*)d_ws;
    // ws layout (4-byte units): norms[4096] | hp[4096] | hn[4096] | hist[256] | part[16]
    float*    norms = ws;
    unsigned* hp    = (unsigned*)(ws + 4096);
    unsigned* hn    = (unsigned*)(ws + 8192);
    int*      hist  = (int*)(ws + 12288);
    float*    part  = ws + 12544;
    float*    out   = (float*)d_out;

    hipLaunchKernelGGL(init_kernel,      dim3(16),     dim3(256), 0, stream, hp, hn, hist);
    hipLaunchKernelGGL(norms_hist_kernel,dim3(NROWS/4),dim3(256), 0, stream, X, labels, norms, hist);
    hipLaunchKernelGGL(dist_kernel,      dim3(64, 64), dim3(256), 0, stream, X, labels, norms, hp, hn);
    hipLaunchKernelGGL(finalize_kernel,  dim3(16),     dim3(256), 0, stream, hp, hn, labels, hist, part);
    hipLaunchKernelGGL(sum_kernel,       dim3(1),      dim3(64),  0, stream, part, out);
}

// Round 2
// 60.069 us; speedup vs baseline: 4.3124x; 4.3124x over previous
//
#include <hip/hip_runtime.h>

#define NROWS 4096
#define DIM   512
#define MARGIN 0.3f

typedef _Float16 f16;
typedef _Float16 f16x8 __attribute__((ext_vector_type(8)));
typedef float    f32x4 __attribute__((ext_vector_type(4)));

// ---------------- init: hp=0 bits, hn=+inf bits, hist=0 ----------------
__global__ void init_kernel(unsigned* hp, unsigned* hn, int* hist) {
    int i = blockIdx.x * blockDim.x + threadIdx.x;
    if (i < NROWS) { hp[i] = 0u; hn[i] = 0x7f800000u; }
    if (i < 256) hist[i] = 0;
}

// ---------------- per-row squared norms (fp32) + label histogram ----------------
__global__ void norms_hist_kernel(const float* __restrict__ X,
                                  const int* __restrict__ labels,
                                  float* __restrict__ norms, int* hist) {
    int wave = threadIdx.x >> 6;
    int lane = threadIdx.x & 63;
    int row  = blockIdx.x * 4 + wave;
    const float4* xr = (const float4*)(X + (size_t)row * DIM);
    float4 a = xr[lane];
    float4 b = xr[lane + 64];
    float s = a.x*a.x + a.y*a.y + a.z*a.z + a.w*a.w
            + b.x*b.x + b.y*b.y + b.z*b.z + b.w*b.w;
    #pragma unroll
    for (int o = 32; o; o >>= 1) s += __shfl_xor(s, o);
    if (lane == 0) {
        norms[row] = s;
        atomicAdd(&hist[labels[row]], 1);
    }
}

// ---------------- fp32 -> fp16 in MFMA-tiled layout ----------------
// Xh layout: tile (R,K0), R=row/128 in [0,32), K0=k/32 in [0,16).
// Tile = 512 units of 16B: unit u = rg*64 + c*16 + r  (rg=rowgrp, c=kchunk, r=row%16)
// element (row = R*128+rg*16+r, k = K0*32+c*8+j) at half index tile*4096 + u*8 + j.
__global__ void convert_kernel(const float* __restrict__ X, f16* __restrict__ Xh) {
    int g = blockIdx.x * 256 + threadIdx.x;         // [0, 262144)
    int tile = g >> 9, u = g & 511;
    int R = tile >> 4, K0 = tile & 15;
    int rg = u >> 6, c = (u >> 4) & 3, r = u & 15;
    int row = R * 128 + rg * 16 + r;
    int k0  = K0 * 32 + c * 8;
    const float4* p = (const float4*)(X + (size_t)row * DIM + k0);
    float4 a = p[0], b = p[1];
    f16x8 h;
    h[0] = (f16)a.x; h[1] = (f16)a.y; h[2] = (f16)a.z; h[3] = (f16)a.w;
    h[4] = (f16)b.x; h[5] = (f16)b.y; h[6] = (f16)b.z; h[7] = (f16)b.w;
    *(f16x8*)(Xh + (size_t)g * 8) = h;
}

__device__ inline void gload_lds16(const f16* g, f16* l) {
    __builtin_amdgcn_global_load_lds(
        (const __attribute__((address_space(1))) void*)g,
        (__attribute__((address_space(3))) void*)l, 16, 0, 0);
}

// ---------------- MFMA fused GEMM + masked row/col max-min ----------------
// Lower-triangle grid (by <= bx). Each 128x128 block: S = Xrow . Xcol^T via
// mfma_f32_16x16x32_f16, then BOTH row-wise and col-wise masked reductions
// (dist symmetric; max/min idempotent so diagonal double-count is harmless).
__global__ __launch_bounds__(256) void mfma_dist_kernel(
        const f16* __restrict__ Xh, const int* __restrict__ labels,
        const float* __restrict__ norms,
        unsigned* __restrict__ hp, unsigned* __restrict__ hn) {
    __shared__ __align__(16) f16 S[8192];   // A: units 0..511, B: units 512..1023

    const int t    = threadIdx.x;
    const int lane = t & 63, w = t >> 6;
    const int l15  = lane & 15, l4 = lane >> 4;

    // linear block id -> (by <= bx)
    int bt = blockIdx.x;
    int bx = (int)((sqrtf(8.0f * bt + 1.0f) - 1.0f) * 0.5f);
    while ((bx + 1) * (bx + 2) / 2 <= bt) ++bx;
    while (bx * (bx + 1) / 2 > bt) --bx;
    int by = bt - bx * (bx + 1) / 2;

    const int wr = w >> 1, wc = w & 1;
    const int qb = w * 256;                  // this wave's 256 staging units

    f32x4 zero = {0.f, 0.f, 0.f, 0.f};
    f32x4 acc[4][4];
    #pragma unroll
    for (int m = 0; m < 4; ++m)
        #pragma unroll
        for (int n = 0; n < 4; ++n) acc[m][n] = zero;

    for (int kt = 0; kt < 16; ++kt) {
        const f16* At = Xh + ((size_t)(by * 16 + kt)) * 4096;
        const f16* Bt = Xh + ((size_t)(bx * 16 + kt)) * 4096;
        #pragma unroll
        for (int c2 = 0; c2 < 4; ++c2) {
            int q = qb + c2 * 64 + lane;
            const f16* src = (q < 512) ? (At + (size_t)q * 8)
                                       : (Bt + (size_t)(q - 512) * 8);
            gload_lds16(src, &S[(size_t)(qb + c2 * 64) * 8]);
        }
        __syncthreads();   // drains vmcnt before barrier

        f16x8 af[4], bf[4];
        #pragma unroll
        for (int m = 0; m < 4; ++m)
            af[m] = *(const f16x8*)&S[(size_t)(((wr * 4 + m) * 64) + l4 * 16 + l15) * 8];
        #pragma unroll
        for (int n = 0; n < 4; ++n)
            bf[n] = *(const f16x8*)&S[(size_t)(512 + (wc * 4 + n) * 64 + l4 * 16 + l15) * 8];
        #pragma unroll
        for (int m = 0; m < 4; ++m)
            #pragma unroll
            for (int n = 0; n < 4; ++n)
                acc[m][n] = __builtin_amdgcn_mfma_f32_16x16x32_f16(af[m], bf[n], acc[m][n], 0, 0, 0);
        __syncthreads();
    }

    // ---- epilogue: sq = ni + nj - 2*dot, masked row & col reduce ----
    const int wrow = by * 128 + wr * 64;
    const int wcol = bx * 128 + wc * 64;
    const float FINF = __uint_as_float(0x7f800000u);

    int lj[4]; float nj[4];
    #pragma unroll
    for (int n = 0; n < 4; ++n) {
        int gc = wcol + n * 16 + l15; lj[n] = labels[gc]; nj[n] = norms[gc];
    }
    int li[16]; float ni[16];
    #pragma unroll
    for (int m = 0; m < 4; ++m)
        #pragma unroll
        for (int r = 0; r < 4; ++r) {
            int gr = wrow + m * 16 + l4 * 4 + r;
            li[m * 4 + r] = labels[gr]; ni[m * 4 + r] = norms[gr];
        }

    float cp[4], cn[4];
    #pragma unroll
    for (int n = 0; n < 4; ++n) { cp[n] = 0.f; cn[n] = FINF; }

    #pragma unroll
    for (int m = 0; m < 4; ++m) {
        #pragma unroll
        for (int r = 0; r < 4; ++r) {
            float rp = 0.f, rn = FINF;
            #pragma unroll
            for (int n = 0; n < 4; ++n) {
                float sq = fmaxf(fmaf(-2.f, acc[m][n][r], ni[m * 4 + r] + nj[n]), 0.f);
                bool same = (li[m * 4 + r] == lj[n]);
                rp = same ? fmaxf(rp, sq) : rp;
                rn = same ? rn : fminf(rn, sq);
                cp[n] = same ? fmaxf(cp[n], sq) : cp[n];
                cn[n] = same ? cn[n] : fminf(cn[n], sq);
            }
            #pragma unroll
            for (int o = 8; o; o >>= 1) {
                rp = fmaxf(rp, __shfl_xor(rp, o));
                rn = fminf(rn, __shfl_xor(rn, o));
            }
            if (l15 == 0) {
                int gr = wrow + m * 16 + l4 * 4 + r;
                atomicMax(&hp[gr], __float_as_uint(rp));
                atomicMin(&hn[gr], __float_as_uint(rn));
            }
        }
    }
    #pragma unroll
    for (int n = 0; n < 4; ++n) {
        float p = cp[n], q = cn[n];
        p = fmaxf(p, __shfl_xor(p, 16)); q = fminf(q, __shfl_xor(q, 16));
        p = fmaxf(p, __shfl_xor(p, 32)); q = fminf(q, __shfl_xor(q, 32));
        if (l4 == 0) {
            int gc = wcol + n * 16 + l15;
            atomicMax(&hp[gc], __float_as_uint(p));
            atomicMin(&hn[gc], __float_as_uint(q));
        }
    }
}

// ---------------- fp32 fallback (round-0 kernel) if ws too small ----------------
#define BK  32
#define PAD 68
__global__ __launch_bounds__(256) void dist_fp32_kernel(
        const float* __restrict__ X, const int* __restrict__ labels,
        const float* __restrict__ norms,
        unsigned* __restrict__ hp, unsigned* __restrict__ hn) {
    __shared__ __align__(16) float As[BK][PAD];
    __shared__ __align__(16) float Bs[BK][PAD];
    const int t  = threadIdx.x;
    const int tx = t & 15, ty = t >> 4;
    const int row0 = blockIdx.y * 64, col0 = blockIdx.x * 64;

    float acc[4][4] = {};
    for (int k0 = 0; k0 < DIM; k0 += BK) {
        #pragma unroll
        for (int l = 0; l < 2; ++l) {
            int idx = t + l * 256;
            int r = idx >> 3, fc = idx & 7;
            float4 va = *(const float4*)(X + (size_t)(row0 + r) * DIM + k0 + fc * 4);
            float4 vb = *(const float4*)(X + (size_t)(col0 + r) * DIM + k0 + fc * 4);
            As[fc*4+0][r] = va.x; As[fc*4+1][r] = va.y;
            As[fc*4+2][r] = va.z; As[fc*4+3][r] = va.w;
            Bs[fc*4+0][r] = vb.x; Bs[fc*4+1][r] = vb.y;
            Bs[fc*4+2][r] = vb.z; Bs[fc*4+3][r] = vb.w;
        }
        __syncthreads();
        #pragma unroll
        for (int kk = 0; kk < BK; ++kk) {
            float4 a = *(const float4*)&As[kk][ty * 4];
            float4 b = *(const float4*)&Bs[kk][tx * 4];
            float av[4] = {a.x, a.y, a.z, a.w};
            float bv[4] = {b.x, b.y, b.z, b.w};
            #pragma unroll
            for (int m = 0; m < 4; ++m)
                #pragma unroll
                for (int n = 0; n < 4; ++n)
                    acc[m][n] = fmaf(av[m], bv[n], acc[m][n]);
        }
        __syncthreads();
    }
    int li[4], lj[4]; float ni[4], nj[4];
    #pragma unroll
    for (int m = 0; m < 4; ++m) {
        int gi = row0 + ty * 4 + m; li[m] = labels[gi]; ni[m] = norms[gi];
    }
    #pragma unroll
    for (int n = 0; n < 4; ++n) {
        int gj = col0 + tx * 4 + n; lj[n] = labels[gj]; nj[n] = norms[gj];
    }
    #pragma unroll
    for (int m = 0; m < 4; ++m) {
        float pmax = 0.0f;
        float nmin = __uint_as_float(0x7f800000u);
        #pragma unroll
        for (int n = 0; n < 4; ++n) {
            float sq = fmaxf(ni[m] + nj[n] - 2.0f * acc[m][n], 0.0f);
            if (li[m] == lj[n]) pmax = fmaxf(pmax, sq);
            else                nmin = fminf(nmin, sq);
        }
        #pragma unroll
        for (int o = 8; o; o >>= 1) {
            pmax = fmaxf(pmax, __shfl_xor(pmax, o));
            nmin = fminf(nmin, __shfl_xor(nmin, o));
        }
        if (tx == 0) {
            int gi = row0 + ty * 4 + m;
            atomicMax(&hp[gi], __float_as_uint(pmax));
            atomicMin(&hn[gi], __float_as_uint(nmin));
        }
    }
}

// ---------------- finalize: per-row loss, 16 block partials ----------------
__global__ void finalize_kernel(const unsigned* __restrict__ hp,
                                const unsigned* __restrict__ hn,
                                const int* __restrict__ labels,
                                const int* __restrict__ hist,
                                float* __restrict__ part) {
    int i = blockIdx.x * 256 + threadIdx.x;
    float hpd = sqrtf(__uint_as_float(hp[i]));
    float hnd = sqrtf(__uint_as_float(hn[i]));
    float v = 0.0f;
    if (hist[labels[i]] > 1) v = fmaxf(hpd - hnd + MARGIN, 0.0f);
    #pragma unroll
    for (int o = 32; o; o >>= 1) v += __shfl_xor(v, o);
    __shared__ float wsum[4];
    int lane = threadIdx.x & 63, wave = threadIdx.x >> 6;
    if (lane == 0) wsum[wave] = v;
    __syncthreads();
    if (threadIdx.x == 0) part[blockIdx.x] = wsum[0] + wsum[1] + wsum[2] + wsum[3];
}

__global__ void sum_kernel(const float* __restrict__ part, float* __restrict__ out) {
    float v = (threadIdx.x < 16) ? part[threadIdx.x] : 0.0f;
    #pragma unroll
    for (int o = 32; o; o >>= 1) v += __shfl_xor(v, o);
    if (threadIdx.x == 0) out[0] = v / (float)NROWS;
}

extern "C" void kernel_launch(void* const* d_in, const int* in_sizes, int n_in,
                              void* d_out, int out_size, void* d_ws, size_t ws_size,
                              hipStream_t stream) {
    const float* X      = (const float*)d_in[0];
    const int*   labels = (const int*)d_in[1];
    float* ws = (float*)d_ws;
    // ws layout (floats): norms[4096] | hp[4096] | hn[4096] | hist[256] | part[16] | pad -> 64KB | Xh (4MB)
    float*    norms = ws;
    unsigned* hp    = (unsigned*)(ws + 4096);
    unsigned* hn    = (unsigned*)(ws + 8192);
    int*      hist  = (int*)(ws + 12288);
    float*    part  = ws + 12544;
    f16*      Xh    = (f16*)((char*)d_ws + 65536);
    float*    out   = (float*)d_out;

    const size_t need = 65536 + (size_t)NROWS * DIM * sizeof(f16);

    hipLaunchKernelGGL(init_kernel,       dim3(16),      dim3(256), 0, stream, hp, hn, hist);
    hipLaunchKernelGGL(norms_hist_kernel, dim3(NROWS/4), dim3(256), 0, stream, X, labels, norms, hist);
    if (ws_size >= need) {
        hipLaunchKernelGGL(convert_kernel,   dim3(1024), dim3(256), 0, stream, X, Xh);
        hipLaunchKernelGGL(mfma_dist_kernel, dim3(528),  dim3(256), 0, stream, Xh, labels, norms, hp, hn);
    } else {
        hipLaunchKernelGGL(dist_fp32_kernel, dim3(64, 64), dim3(256), 0, stream, X, labels, norms, hp, hn);
    }
    hipLaunchKernelGGL(finalize_kernel,   dim3(16), dim3(256), 0, stream, hp, hn, labels, hist, part);
    hipLaunchKernelGGL(sum_kernel,        dim3(1),  dim3(64),  0, stream, part, out);
}

// Round 3
// 41.564 us; speedup vs baseline: 6.2323x; 1.4452x over previous
//
#include <hip/hip_runtime.h>

#define NROWS 4096
#define DIM   512
#define MARGIN 0.3f

typedef _Float16 f16;
typedef _Float16 f16x8 __attribute__((ext_vector_type(8)));
typedef float    f32x4 __attribute__((ext_vector_type(4)));

// ---------------- per-row squared norms (fp32) + hp/hn init ----------------
__global__ void norms_init_kernel(const float* __restrict__ X,
                                  float* __restrict__ norms,
                                  unsigned* __restrict__ hp, unsigned* __restrict__ hn) {
    int wave = threadIdx.x >> 6;
    int lane = threadIdx.x & 63;
    int row  = blockIdx.x * 4 + wave;
    const float4* xr = (const float4*)(X + (size_t)row * DIM);
    float4 a = xr[lane];
    float4 b = xr[lane + 64];
    float s = a.x*a.x + a.y*a.y + a.z*a.z + a.w*a.w
            + b.x*b.x + b.y*b.y + b.z*b.z + b.w*b.w;
    #pragma unroll
    for (int o = 32; o; o >>= 1) s += __shfl_xor(s, o);
    if (lane == 0) norms[row] = s;
    // hp/hn init (consumed only by later kernels -> no race)
    int g = blockIdx.x * 256 + threadIdx.x;
    if (g < NROWS) { hp[g] = 0u; hn[g] = 0x7f800000u; }
}

// ---------------- fp32 -> fp16 in MFMA-tiled layout ----------------
// Xh layout: tile (R,K0), R=row/128 in [0,32), K0=k/32 in [0,16).
// Tile = 512 units of 16B: unit u = rg*64 + c*16 + r  (rg=rowgrp, c=kchunk, r=row%16)
// element (row = R*128+rg*16+r, k = K0*32+c*8+j) at half index tile*4096 + u*8 + j.
__global__ void convert_kernel(const float* __restrict__ X, f16* __restrict__ Xh) {
    int g = blockIdx.x * 256 + threadIdx.x;         // [0, 262144)
    int tile = g >> 9, u = g & 511;
    int R = tile >> 4, K0 = tile & 15;
    int rg = u >> 6, c = (u >> 4) & 3, r = u & 15;
    int row = R * 128 + rg * 16 + r;
    int k0  = K0 * 32 + c * 8;
    const float4* p = (const float4*)(X + (size_t)row * DIM + k0);
    float4 a = p[0], b = p[1];
    f16x8 h;
    h[0] = (f16)a.x; h[1] = (f16)a.y; h[2] = (f16)a.z; h[3] = (f16)a.w;
    h[4] = (f16)b.x; h[5] = (f16)b.y; h[6] = (f16)b.z; h[7] = (f16)b.w;
    *(f16x8*)(Xh + (size_t)g * 8) = h;
}

__device__ inline void gload_lds16(const f16* g, f16* l) {
    __builtin_amdgcn_global_load_lds(
        (const __attribute__((address_space(1))) void*)g,
        (__attribute__((address_space(3))) void*)l, 16, 0, 0);
}

// stage one 128x32 A-tile + B-tile pair into buf; wave w covers units [qb, qb+256)
__device__ inline void stage_tile(const f16* __restrict__ At, const f16* __restrict__ Bt,
                                  f16* buf, int qb, int lane) {
    const f16* base = (qb < 512) ? (At + (size_t)qb * 8) : (Bt + (size_t)(qb - 512) * 8);
    #pragma unroll
    for (int c2 = 0; c2 < 4; ++c2)
        gload_lds16(base + (size_t)(c2 * 64 + lane) * 8, buf + (size_t)(qb + c2 * 64) * 8);
}

// ---------------- MFMA fused GEMM + masked row/col max-min ----------------
// Lower-triangle grid (by <= bx); 128x128 tile, 4 waves, 2-phase double-buffered
// pipeline: stage(next) issued before ds_read+MFMA(cur); single barrier per K-step
// (compiler emits vmcnt(0) before s_barrier, after the MFMA cluster).
__global__ __launch_bounds__(256, 3) void mfma_dist_kernel(
        const f16* __restrict__ Xh, const int* __restrict__ labels,
        const float* __restrict__ norms,
        unsigned* __restrict__ hp, unsigned* __restrict__ hn) {
    __shared__ __align__(16) f16 S0[8192];
    __shared__ __align__(16) f16 S1[8192];

    const int t    = threadIdx.x;
    const int lane = t & 63, w = t >> 6;
    const int l15  = lane & 15, l4 = lane >> 4;

    // linear block id -> (by <= bx)
    int bt = blockIdx.x;
    int bx = (int)((sqrtf(8.0f * bt + 1.0f) - 1.0f) * 0.5f);
    while ((bx + 1) * (bx + 2) / 2 <= bt) ++bx;
    while (bx * (bx + 1) / 2 > bt) --bx;
    int by = bt - bx * (bx + 1) / 2;

    const int wr = w >> 1, wc = w & 1;
    const int qb = w * 256;

    const f16* Abase = Xh + (size_t)(by * 16) * 4096;
    const f16* Bbase = Xh + (size_t)(bx * 16) * 4096;

    f32x4 zero = {0.f, 0.f, 0.f, 0.f};
    f32x4 acc[4][4];
    #pragma unroll
    for (int m = 0; m < 4; ++m)
        #pragma unroll
        for (int n = 0; n < 4; ++n) acc[m][n] = zero;

    stage_tile(Abase, Bbase, S0, qb, lane);
    __syncthreads();

    #pragma unroll
    for (int kt = 0; kt < 16; ++kt) {
        f16* cur = (kt & 1) ? S1 : S0;
        f16* nxt = (kt & 1) ? S0 : S1;
        if (kt < 15)
            stage_tile(Abase + (size_t)(kt + 1) * 4096,
                       Bbase + (size_t)(kt + 1) * 4096, nxt, qb, lane);
        f16x8 af[4], bf[4];
        #pragma unroll
        for (int m = 0; m < 4; ++m)
            af[m] = *(const f16x8*)&cur[(size_t)((wr * 4 + m) * 64 + l4 * 16 + l15) * 8];
        #pragma unroll
        for (int n = 0; n < 4; ++n)
            bf[n] = *(const f16x8*)&cur[(size_t)(512 + (wc * 4 + n) * 64 + l4 * 16 + l15) * 8];
        #pragma unroll
        for (int m = 0; m < 4; ++m)
            #pragma unroll
            for (int n = 0; n < 4; ++n)
                acc[m][n] = __builtin_amdgcn_mfma_f32_16x16x32_f16(af[m], bf[n], acc[m][n], 0, 0, 0);
        if (kt < 15) __syncthreads();
    }

    // ---- epilogue: sq = ni + nj - 2*dot, masked row & col reduce ----
    const int wrow = by * 128 + wr * 64;
    const int wcol = bx * 128 + wc * 64;
    const float FINF = __uint_as_float(0x7f800000u);

    int lj[4]; float nj[4];
    #pragma unroll
    for (int n = 0; n < 4; ++n) {
        int gc = wcol + n * 16 + l15; lj[n] = labels[gc]; nj[n] = norms[gc];
    }
    int li[16]; float ni[16];
    #pragma unroll
    for (int m = 0; m < 4; ++m)
        #pragma unroll
        for (int r = 0; r < 4; ++r) {
            int gr = wrow + m * 16 + l4 * 4 + r;
            li[m * 4 + r] = labels[gr]; ni[m * 4 + r] = norms[gr];
        }

    float cp[4], cn[4];
    #pragma unroll
    for (int n = 0; n < 4; ++n) { cp[n] = 0.f; cn[n] = FINF; }

    #pragma unroll
    for (int m = 0; m < 4; ++m) {
        #pragma unroll
        for (int r = 0; r < 4; ++r) {
            float rp = 0.f, rn = FINF;
            #pragma unroll
            for (int n = 0; n < 4; ++n) {
                float sq = fmaxf(fmaf(-2.f, acc[m][n][r], ni[m * 4 + r] + nj[n]), 0.f);
                bool same = (li[m * 4 + r] == lj[n]);
                rp = same ? fmaxf(rp, sq) : rp;
                rn = same ? rn : fminf(rn, sq);
                cp[n] = same ? fmaxf(cp[n], sq) : cp[n];
                cn[n] = same ? cn[n] : fminf(cn[n], sq);
            }
            #pragma unroll
            for (int o = 8; o; o >>= 1) {
                rp = fmaxf(rp, __shfl_xor(rp, o));
                rn = fminf(rn, __shfl_xor(rn, o));
            }
            if (l15 == 0) {
                int gr = wrow + m * 16 + l4 * 4 + r;
                atomicMax(&hp[gr], __float_as_uint(rp));
                atomicMin(&hn[gr], __float_as_uint(rn));
            }
        }
    }
    #pragma unroll
    for (int n = 0; n < 4; ++n) {
        float p = cp[n], q = cn[n];
        p = fmaxf(p, __shfl_xor(p, 16)); q = fminf(q, __shfl_xor(q, 16));
        p = fmaxf(p, __shfl_xor(p, 32)); q = fminf(q, __shfl_xor(q, 32));
        if (l4 == 0) {
            int gc = wcol + n * 16 + l15;
            atomicMax(&hp[gc], __float_as_uint(p));
            atomicMin(&hn[gc], __float_as_uint(q));
        }
    }
}

// ---------------- fp32 fallback if ws too small for Xh ----------------
#define BK  32
#define PAD 68
__global__ __launch_bounds__(256) void dist_fp32_kernel(
        const float* __restrict__ X, const int* __restrict__ labels,
        const float* __restrict__ norms,
        unsigned* __restrict__ hp, unsigned* __restrict__ hn) {
    __shared__ __align__(16) float As[BK][PAD];
    __shared__ __align__(16) float Bs[BK][PAD];
    const int t  = threadIdx.x;
    const int tx = t & 15, ty = t >> 4;
    const int row0 = blockIdx.y * 64, col0 = blockIdx.x * 64;

    float acc[4][4] = {};
    for (int k0 = 0; k0 < DIM; k0 += BK) {
        #pragma unroll
        for (int l = 0; l < 2; ++l) {
            int idx = t + l * 256;
            int r = idx >> 3, fc = idx & 7;
            float4 va = *(const float4*)(X + (size_t)(row0 + r) * DIM + k0 + fc * 4);
            float4 vb = *(const float4*)(X + (size_t)(col0 + r) * DIM + k0 + fc * 4);
            As[fc*4+0][r] = va.x; As[fc*4+1][r] = va.y;
            As[fc*4+2][r] = va.z; As[fc*4+3][r] = va.w;
            Bs[fc*4+0][r] = vb.x; Bs[fc*4+1][r] = vb.y;
            Bs[fc*4+2][r] = vb.z; Bs[fc*4+3][r] = vb.w;
        }
        __syncthreads();
        #pragma unroll
        for (int kk = 0; kk < BK; ++kk) {
            float4 a = *(const float4*)&As[kk][ty * 4];
            float4 b = *(const float4*)&Bs[kk][tx * 4];
            float av[4] = {a.x, a.y, a.z, a.w};
            float bv[4] = {b.x, b.y, b.z, b.w};
            #pragma unroll
            for (int m = 0; m < 4; ++m)
                #pragma unroll
                for (int n = 0; n < 4; ++n)
                    acc[m][n] = fmaf(av[m], bv[n], acc[m][n]);
        }
        __syncthreads();
    }
    int li[4], lj[4]; float ni[4], nj[4];
    #pragma unroll
    for (int m = 0; m < 4; ++m) {
        int gi = row0 + ty * 4 + m; li[m] = labels[gi]; ni[m] = norms[gi];
    }
    #pragma unroll
    for (int n = 0; n < 4; ++n) {
        int gj = col0 + tx * 4 + n; lj[n] = labels[gj]; nj[n] = norms[gj];
    }
    #pragma unroll
    for (int m = 0; m < 4; ++m) {
        float pmax = 0.0f;
        float nmin = __uint_as_float(0x7f800000u);
        #pragma unroll
        for (int n = 0; n < 4; ++n) {
            float sq = fmaxf(ni[m] + nj[n] - 2.0f * acc[m][n], 0.0f);
            if (li[m] == lj[n]) pmax = fmaxf(pmax, sq);
            else                nmin = fminf(nmin, sq);
        }
        #pragma unroll
        for (int o = 8; o; o >>= 1) {
            pmax = fmaxf(pmax, __shfl_xor(pmax, o));
            nmin = fminf(nmin, __shfl_xor(nmin, o));
        }
        if (tx == 0) {
            int gi = row0 + ty * 4 + m;
            atomicMax(&hp[gi], __float_as_uint(pmax));
            atomicMin(&hn[gi], __float_as_uint(nmin));
        }
    }
}

// ---------------- finalize: hist in LDS + per-row loss + full reduce ----------------
__global__ __launch_bounds__(1024) void finalize_kernel(
        const unsigned* __restrict__ hp, const unsigned* __restrict__ hn,
        const int* __restrict__ labels, float* __restrict__ out) {
    __shared__ int hist[256];
    __shared__ float wsum[16];
    int t = threadIdx.x;
    if (t < 256) hist[t] = 0;
    __syncthreads();
    int4 lab = ((const int4*)labels)[t];
    atomicAdd(&hist[lab.x], 1); atomicAdd(&hist[lab.y], 1);
    atomicAdd(&hist[lab.z], 1); atomicAdd(&hist[lab.w], 1);
    __syncthreads();
    uint4 hp4 = ((const uint4*)hp)[t];
    uint4 hn4 = ((const uint4*)hn)[t];
    int      lv[4]  = {lab.x, lab.y, lab.z, lab.w};
    unsigned hpv[4] = {hp4.x, hp4.y, hp4.z, hp4.w};
    unsigned hnv[4] = {hn4.x, hn4.y, hn4.z, hn4.w};
    float v = 0.f;
    #pragma unroll
    for (int j = 0; j < 4; ++j) {
        float hpd = sqrtf(__uint_as_float(hpv[j]));
        float hnd = sqrtf(__uint_as_float(hnv[j]));   // may be +inf
        if (hist[lv[j]] > 1) v += fmaxf(hpd - hnd + MARGIN, 0.f);
    }
    #pragma unroll
    for (int o = 32; o; o >>= 1) v += __shfl_xor(v, o);
    int lane = t & 63, wv = t >> 6;
    if (lane == 0) wsum[wv] = v;
    __syncthreads();
    if (t == 0) {
        float s = 0.f;
        #pragma unroll
        for (int i = 0; i < 16; ++i) s += wsum[i];
        out[0] = s / (float)NROWS;
    }
}

extern "C" void kernel_launch(void* const* d_in, const int* in_sizes, int n_in,
                              void* d_out, int out_size, void* d_ws, size_t ws_size,
                              hipStream_t stream) {
    const float* X      = (const float*)d_in[0];
    const int*   labels = (const int*)d_in[1];
    float* ws = (float*)d_ws;
    // ws (floats): norms[4096] | hp[4096] | hn[4096] | pad -> 64KB | Xh (4MB)
    float*    norms = ws;
    unsigned* hp    = (unsigned*)(ws + 4096);
    unsigned* hn    = (unsigned*)(ws + 8192);
    f16*      Xh    = (f16*)((char*)d_ws + 65536);
    float*    out   = (float*)d_out;

    const size_t need = 65536 + (size_t)NROWS * DIM * sizeof(f16);

    hipLaunchKernelGGL(norms_init_kernel, dim3(NROWS/4), dim3(256), 0, stream, X, norms, hp, hn);
    if (ws_size >= need) {
        hipLaunchKernelGGL(convert_kernel,   dim3(1024), dim3(256), 0, stream, X, Xh);
        hipLaunchKernelGGL(mfma_dist_kernel, dim3(528),  dim3(256), 0, stream, Xh, labels, norms, hp, hn);
    } else {
        hipLaunchKernelGGL(dist_fp32_kernel, dim3(64, 64), dim3(256), 0, stream, X, labels, norms, hp, hn);
    }
    hipLaunchKernelGGL(finalize_kernel, dim3(1), dim3(1024), 0, stream, hp, hn, labels, out);
}